// Round 1
// baseline (596.376 us; speedup 1.0000x reference)
//
#include <hip/hip_runtime.h>
#include <hip/hip_bf16.h>

#define B_   32
#define S_   512
#define D_   256
#define H_   8
#define E_   32
#define FF_  1024
#define T_   (B_ * S_)   // 16384 tokens

// ---------------------------------------------------------------------------
// Pack wq/wk/wv [H][D][E] into Wp[K=256][N=768], n = which*256 + h*32 + e
// ---------------------------------------------------------------------------
__global__ void pack_qkv_w(const float* __restrict__ wq, const float* __restrict__ wk,
                           const float* __restrict__ wv, float* __restrict__ Wp) {
    int idx = blockIdx.x * 256 + threadIdx.x;
    if (idx >= 256 * 768) return;
    int k = idx / 768, n = idx % 768;
    int which = n >> 8, r = n & 255, h = r >> 5, e = r & 31;
    const float* w = (which == 0) ? wq : (which == 1 ? wk : wv);
    Wp[idx] = w[(h * D_ + k) * E_ + e];
}

// ---------------------------------------------------------------------------
// fp32 tiled GEMM: C[M][N] = A[M][K] @ B[K][N]  (+bias, +relu per EP)
// BM=BN=64, BK=16, 256 threads, 4x4 outputs/thread.
// M,N,K all multiples of tile sizes here -> no bounds checks.
// EP: 0 = none, 1 = +bias, 2 = +bias+relu
// ---------------------------------------------------------------------------
template <int EP>
__global__ __launch_bounds__(256) void gemm_f32(const float* __restrict__ A,
                                                const float* __restrict__ Bm,
                                                const float* __restrict__ bias,
                                                float* __restrict__ C,
                                                int M, int N, int K) {
    const int BM = 64, BN = 64, BK = 16;
    __shared__ float As[BK][BM + 4];   // transposed A tile, padded (stride 68: 2-way max)
    __shared__ float Bs[BK][BN];
    int bm = blockIdx.y * BM, bn = blockIdx.x * BN;
    int tid = threadIdx.x;
    int tx = tid & 15, ty = tid >> 4;

    float acc[4][4] = {};

    for (int k0 = 0; k0 < K; k0 += BK) {
        {   // A tile: 64 rows x 16 cols; thread -> (row=tid/4, 4 cols)
            int row = tid >> 2, c = (tid & 3) << 2;
            float4 a4 = *(const float4*)&A[(size_t)(bm + row) * K + k0 + c];
            As[c + 0][row] = a4.x; As[c + 1][row] = a4.y;
            As[c + 2][row] = a4.z; As[c + 3][row] = a4.w;
        }
        {   // B tile: 16 rows x 64 cols; thread -> (row=tid/16, 4 cols)
            int row = tid >> 4, c = (tid & 15) << 2;
            *(float4*)&Bs[row][c] = *(const float4*)&Bm[(size_t)(k0 + row) * N + bn + c];
        }
        __syncthreads();
        #pragma unroll
        for (int k = 0; k < BK; ++k) {
            float4 av = *(const float4*)&As[k][ty * 4];
            float4 bv = *(const float4*)&Bs[k][tx * 4];
            float a[4] = {av.x, av.y, av.z, av.w};
            float b[4] = {bv.x, bv.y, bv.z, bv.w};
            #pragma unroll
            for (int i = 0; i < 4; ++i)
                #pragma unroll
                for (int j = 0; j < 4; ++j)
                    acc[i][j] += a[i] * b[j];
        }
        __syncthreads();
    }

    #pragma unroll
    for (int i = 0; i < 4; ++i) {
        float4 o;
        float* orow = &C[(size_t)(bm + ty * 4 + i) * N + bn + tx * 4];
        float r[4];
        #pragma unroll
        for (int j = 0; j < 4; ++j) {
            float v = acc[i][j];
            if (EP >= 1) v += bias[bn + tx * 4 + j];
            if (EP == 2) v = fmaxf(v, 0.f);
            r[j] = v;
        }
        o.x = r[0]; o.y = r[1]; o.z = r[2]; o.w = r[3];
        *(float4*)orow = o;
    }
}

// ---------------------------------------------------------------------------
// Causal attention, one workgroup per (b,h). K/V rows staged in LDS (128 KB).
// 4 waves; wave w handles row-chunks {w, 7-w} (64 rows each, lane = row).
// Flash-style online softmax with deferred (threshold-8) rescale.
// ---------------------------------------------------------------------------
__global__ __launch_bounds__(256) void attn_kernel(const float* __restrict__ qkv,
                                                   float* __restrict__ ctx) {
    __shared__ float Ks[S_][E_];   // 64 KB
    __shared__ float Vs[S_][E_];   // 64 KB
    int bh = blockIdx.x;
    int b = bh >> 3, h = bh & 7;
    const float scale = 0.17677669529663687f;  // 1/sqrt(32)

    const float* kbase = qkv + (size_t)b * S_ * 768 + 256 + h * 32;
    const float* vbase = qkv + (size_t)b * S_ * 768 + 512 + h * 32;
    for (int t = threadIdx.x >> 3; t < S_; t += 32) {
        int c = (threadIdx.x & 7) << 2;
        *(float4*)&Ks[t][c] = *(const float4*)&kbase[(size_t)t * 768 + c];
        *(float4*)&Vs[t][c] = *(const float4*)&vbase[(size_t)t * 768 + c];
    }
    __syncthreads();

    int waveId = threadIdx.x >> 6, lane = threadIdx.x & 63;

    for (int rep = 0; rep < 2; ++rep) {
        int chunk = (rep == 0) ? waveId : (7 - waveId);
        int s = chunk * 64 + lane;

        float q[32];
        const float* qrow = qkv + (size_t)(b * S_ + s) * 768 + h * 32;
        #pragma unroll
        for (int i = 0; i < 8; ++i) {
            float4 t4 = *(const float4*)&qrow[i * 4];
            q[i * 4 + 0] = t4.x * scale; q[i * 4 + 1] = t4.y * scale;
            q[i * 4 + 2] = t4.z * scale; q[i * 4 + 3] = t4.w * scale;
        }

        float m = -1e30f, l = 0.f, O[32] = {};
        int tend = chunk * 64 + 64;
        for (int t = 0; t < tend; ++t) {
            const float* kr = &Ks[t][0];
            float d0 = 0.f, d1 = 0.f, d2 = 0.f, d3 = 0.f;
            #pragma unroll
            for (int k = 0; k < 32; k += 4) {
                d0 += q[k + 0] * kr[k + 0];
                d1 += q[k + 1] * kr[k + 1];
                d2 += q[k + 2] * kr[k + 2];
                d3 += q[k + 3] * kr[k + 3];
            }
            float sc = (d0 + d1) + (d2 + d3);
            sc = (t <= s) ? sc : -1e30f;

            if (__any(sc > m + 8.f)) {   // deferred rescale (rare after warm-up)
                float mn = fmaxf(m, sc);
                float corr = __expf(m - mn);
                l *= corr;
                #pragma unroll
                for (int k = 0; k < 32; ++k) O[k] *= corr;
                m = mn;
            }
            float p = __expf(sc - m);    // masked lanes: exp(-huge) = 0
            l += p;
            const float* vr = &Vs[t][0];
            #pragma unroll
            for (int k = 0; k < 32; ++k) O[k] += p * vr[k];
        }

        float inv = 1.f / l;
        float* orow = ctx + (size_t)(b * S_ + s) * D_ + h * 32;
        #pragma unroll
        for (int i = 0; i < 8; ++i) {
            float4 o;
            o.x = O[i * 4 + 0] * inv; o.y = O[i * 4 + 1] * inv;
            o.z = O[i * 4 + 2] * inv; o.w = O[i * 4 + 3] * inv;
            *(float4*)&orow[i * 4] = o;
        }
    }
}

// ---------------------------------------------------------------------------
// out[t] = x[t] + LayerNorm(in[t]) * g + be   (row = 256, one wave per token)
// ---------------------------------------------------------------------------
__global__ __launch_bounds__(256) void ln_residual(const float* __restrict__ in,
                                                   const float* __restrict__ x,
                                                   const float* __restrict__ g,
                                                   const float* __restrict__ be,
                                                   float* __restrict__ out) {
    int token = blockIdx.x * 4 + (threadIdx.x >> 6);
    int lane = threadIdx.x & 63;
    const float* row = in + (size_t)token * D_;
    float4 v = *(const float4*)&row[lane * 4];
    float s  = v.x + v.y + v.z + v.w;
    float s2 = v.x * v.x + v.y * v.y + v.z * v.z + v.w * v.w;
    #pragma unroll
    for (int off = 1; off < 64; off <<= 1) {
        s  += __shfl_xor(s, off);
        s2 += __shfl_xor(s2, off);
    }
    float mu  = s * (1.f / D_);
    float var = s2 * (1.f / D_) - mu * mu;
    float r   = rsqrtf(var + 1e-5f);
    float4 xv = *(const float4*)&x[(size_t)token * D_ + lane * 4];
    float4 gv = *(const float4*)&g[lane * 4];
    float4 bv = *(const float4*)&be[lane * 4];
    float4 o;
    o.x = xv.x + (v.x - mu) * r * gv.x + bv.x;
    o.y = xv.y + (v.y - mu) * r * gv.y + bv.y;
    o.z = xv.z + (v.z - mu) * r * gv.z + bv.z;
    o.w = xv.w + (v.w - mu) * r * gv.w + bv.w;
    *(float4*)&out[(size_t)token * D_ + lane * 4] = o;
}

// ---------------------------------------------------------------------------
extern "C" void kernel_launch(void* const* d_in, const int* in_sizes, int n_in,
                              void* d_out, int out_size, void* d_ws, size_t ws_size,
                              hipStream_t stream) {
    (void)in_sizes; (void)n_in; (void)out_size; (void)ws_size;
    const float* x      = (const float*)d_in[0];
    const float* wq     = (const float*)d_in[1];
    const float* wk     = (const float*)d_in[2];
    const float* wv     = (const float*)d_in[3];
    const float* w_proj = (const float*)d_in[4];
    const float* w1     = (const float*)d_in[5];
    const float* b1     = (const float*)d_in[6];
    const float* w2     = (const float*)d_in[7];
    const float* b2     = (const float*)d_in[8];
    const float* g1     = (const float*)d_in[9];
    const float* be1    = (const float*)d_in[10];
    const float* g2     = (const float*)d_in[11];
    const float* be2    = (const float*)d_in[12];
    float* out = (float*)d_out;

    // workspace layout (floats), regions reused once consumed; peak 80 MB
    float* ws      = (float*)d_ws;
    float* qkv     = ws;                  // [0, 12582912)   T*768
    float* Wp      = ws + 12582912;       // [12582912, 12779520)  (dead after qkv GEMM)
    float* ctxbuf  = ws + 12582912;       // [12582912, 16777216)  T*256 (over Wp)
    float* attnout = ws;                  // [0, 4194304)          (over qkv)
    float* h       = ws + 16777216;       // [16777216, 20971520)  T*256
    float* ff1     = ws;                  // [0, 16777216)         T*1024 (over attnout/ctx)
    float* ffout   = ws + 16777216;       // over h (h dead after ff1 GEMM)

    pack_qkv_w<<<768, 256, 0, stream>>>(wq, wk, wv, Wp);

    // QKV projection: [16384,256] @ [256,768]
    gemm_f32<0><<<dim3(768 / 64, T_ / 64), 256, 0, stream>>>(x, Wp, nullptr, qkv, T_, 768, D_);

    // causal attention per (b,h)
    attn_kernel<<<B_ * H_, 256, 0, stream>>>(qkv, ctxbuf);

    // output projection: [16384,256] @ [256,256]
    gemm_f32<0><<<dim3(D_ / 64, T_ / 64), 256, 0, stream>>>(ctxbuf, w_proj, nullptr, attnout, T_, D_, D_);

    // h = x + LN1(attnout)
    ln_residual<<<T_ / 4, 256, 0, stream>>>(attnout, x, g1, be1, h);

    // ff1 = relu(h @ w1 + b1): [16384,256] @ [256,1024]
    gemm_f32<2><<<dim3(FF_ / 64, T_ / 64), 256, 0, stream>>>(h, w1, b1, ff1, T_, FF_, D_);

    // ffout = ff1 @ w2 + b2: [16384,1024] @ [1024,256]
    gemm_f32<1><<<dim3(D_ / 64, T_ / 64), 256, 0, stream>>>(ff1, w2, b2, ffout, T_, D_, FF_);

    // out = x + LN2(ffout)
    ln_residual<<<T_ / 4, 256, 0, stream>>>(ffout, x, g2, be2, out);
}

// Round 2
// 412.043 us; speedup vs baseline: 1.4474x; 1.4474x over previous
//
#include <hip/hip_runtime.h>
#include <hip/hip_bf16.h>

#define B_   32
#define S_   512
#define D_   256
#define H_   8
#define E_   32
#define FF_  1024
#define T_   (B_ * S_)   // 16384 tokens

typedef __attribute__((ext_vector_type(8))) short short8;
typedef __attribute__((ext_vector_type(4))) float f32x4;

// round-to-nearest-even fp32 -> bf16 (bit-level, no API dependence)
static __device__ __forceinline__ unsigned short f2bf(float f) {
    union { float f; unsigned int u; } c; c.f = f;
    unsigned int u = c.u;
    u += 0x7fffu + ((u >> 16) & 1u);
    return (unsigned short)(u >> 16);
}

#define GLOAD16(g, l) __builtin_amdgcn_global_load_lds( \
    (const __attribute__((address_space(1))) void*)(g), \
    (__attribute__((address_space(3))) void*)(l), 16, 0, 0)

// ---------------------------------------------------------------------------
// fp32 -> bf16 elementwise (n multiple of 4)
// ---------------------------------------------------------------------------
__global__ void f2b_kernel(const float* __restrict__ in, unsigned short* __restrict__ outp, int n4) {
    int i = blockIdx.x * 256 + threadIdx.x;
    if (i >= n4) return;
    float4 v = *(const float4*)&in[(size_t)i * 4];
    ushort4 o; o.x = f2bf(v.x); o.y = f2bf(v.y); o.z = f2bf(v.z); o.w = f2bf(v.w);
    *(ushort4*)&outp[(size_t)i * 4] = o;
}

// wq/wk/wv [H][D][E] -> Wt[768][256] bf16, row n = which*256 + h*32 + e, col k = d
__global__ void pack_qkvw(const float* __restrict__ wq, const float* __restrict__ wk,
                          const float* __restrict__ wv, unsigned short* __restrict__ Wt) {
    int idx = blockIdx.x * 256 + threadIdx.x;   // 768*256
    int nn = idx >> 8, k = idx & 255;
    int which = nn >> 8, r = nn & 255, h = r >> 5, e = r & 31;
    const float* w = (which == 0) ? wq : (which == 1 ? wk : wv);
    Wt[idx] = f2bf(w[(h * D_ + k) * E_ + e]);
}

// w [K][N] fp32 -> Wt [N][K] bf16
__global__ void pack_t(const float* __restrict__ w, unsigned short* __restrict__ Wt, int K, int N) {
    int idx = blockIdx.x * 256 + threadIdx.x;
    if (idx >= N * K) return;
    int nn = idx / K, k = idx - nn * K;
    Wt[idx] = f2bf(w[(size_t)k * N + nn]);
}

// ---------------------------------------------------------------------------
// bf16 MFMA GEMM: C[M][N] = A[M][K] @ Bt[N][K]^T, fp32 accumulate.
// BM=BN=128, BK=32, 256 threads (4 waves, 2x2 grid of 64x64 per wave).
// LDS: linear [128][32] bf16 tiles, XOR-swizzled 16B chunks (c ^= (row>>1)&3)
// via pre-swizzled global source + swizzled ds_read (rule #21).
// EP bits: 1=bias, 2=relu, 4=bf16 output
// ---------------------------------------------------------------------------
template <int EP>
__global__ __launch_bounds__(256) void gemm_mfma(const unsigned short* __restrict__ A,
                                                 const unsigned short* __restrict__ Bt,
                                                 const float* __restrict__ bias,
                                                 void* __restrict__ Cout,
                                                 int M, int N, int K) {
    __shared__ char smem[32768];   // [buf][A:8KB | B:8KB] x2
    const int tid = threadIdx.x;
    const int bm = blockIdx.y * 128, bn = blockIdx.x * 128;
    const int wave = tid >> 6, lane = tid & 63;
    const int l15 = lane & 15, kc = lane >> 4;          // frag row-in-16 / k-chunk
    const int wr = (wave >> 1) * 64, wc = (wave & 1) * 64;

    auto stage = [&](int buf, int kt) {
        int k0 = kt * 32;
        char* aBase = smem + buf * 8192;
        char* bBase = smem + 16384 + buf * 8192;
        #pragma unroll
        for (int j = 0; j < 2; ++j) {
            int o = j * 256 + tid;          // 16B-slot index 0..511
            int r = o >> 2, c = o & 3;
            int g = c ^ ((r >> 1) & 3);     // inverse-swizzled source chunk
            GLOAD16(A + (size_t)(bm + r) * K + k0 + g * 8, aBase + o * 16);
            GLOAD16(Bt + (size_t)(bn + r) * K + k0 + g * 8, bBase + o * 16);
        }
    };

    f32x4 acc[4][4];
    #pragma unroll
    for (int m = 0; m < 4; ++m)
        #pragma unroll
        for (int n = 0; n < 4; ++n) acc[m][n] = (f32x4){0.f, 0.f, 0.f, 0.f};

    const int NT = K >> 5;
    stage(0, 0);
    __syncthreads();

    int buf = 0;
    for (int kt = 0; kt < NT; ++kt) {
        if (kt + 1 < NT) stage(buf ^ 1, kt + 1);
        const char* aBase = smem + buf * 8192;
        const char* bBase = smem + 16384 + buf * 8192;
        short8 afr[4], bfr[4];
        #pragma unroll
        for (int m = 0; m < 4; ++m) {
            int row = wr + m * 16 + l15;
            int cc = kc ^ ((row >> 1) & 3);
            afr[m] = *(const short8*)(aBase + row * 64 + cc * 16);
        }
        #pragma unroll
        for (int n = 0; n < 4; ++n) {
            int row = wc + n * 16 + l15;
            int cc = kc ^ ((row >> 1) & 3);
            bfr[n] = *(const short8*)(bBase + row * 64 + cc * 16);
        }
        #pragma unroll
        for (int m = 0; m < 4; ++m)
            #pragma unroll
            for (int n = 0; n < 4; ++n)
                acc[m][n] = __builtin_amdgcn_mfma_f32_16x16x32_bf16(afr[m], bfr[n], acc[m][n], 0, 0, 0);
        __syncthreads();
        buf ^= 1;
    }

    // epilogue: C row = bm+wr+m*16+kc*4+j, col = bn+wc+n*16+l15  (m89-verified C/D map)
    #pragma unroll
    for (int n = 0; n < 4; ++n) {
        int col = bn + wc + n * 16 + l15;
        float bv = (EP & 1) ? bias[col] : 0.f;
        #pragma unroll
        for (int m = 0; m < 4; ++m) {
            int row0 = bm + wr + m * 16 + kc * 4;
            #pragma unroll
            for (int j = 0; j < 4; ++j) {
                float v = acc[m][n][j] + bv;
                if (EP & 2) v = fmaxf(v, 0.f);
                if (EP & 4) ((unsigned short*)Cout)[(size_t)(row0 + j) * N + col] = f2bf(v);
                else        ((float*)Cout)[(size_t)(row0 + j) * N + col] = v;
            }
        }
    }
}

// ---------------------------------------------------------------------------
// Causal attention. Grid = B*H*4 blocks; block handles chunk-pair {p, 7-p}
// of one (b,h) (64 q-rows each, lane = row). The 4 waves split the kv range
// into equal quarters with flash partials, combined through LDS.
// K/V read directly from global (L2-resident; wave-uniform row address).
// Writes ctx as bf16 [T][256].
// ---------------------------------------------------------------------------
__global__ __launch_bounds__(256) void attn_kernel(const float* __restrict__ qkv,
                                                   unsigned short* __restrict__ ctx) {
    __shared__ float Ols[4][64][32];  // 32 KB
    __shared__ float Mls[4][64];
    __shared__ float Lls[4][64];
    int blk = blockIdx.x;
    int bh = blk >> 2, pair = blk & 3;
    int b = bh >> 3, h = bh & 7;
    int wave = threadIdx.x >> 6, lane = threadIdx.x & 63;
    const float scale = 0.17677669529663687f;  // 1/sqrt(32)
    const float* base = qkv + (size_t)b * S_ * 768;

    for (int rep = 0; rep < 2; ++rep) {
        int chunk = (rep == 0) ? pair : 7 - pair;
        int s = chunk * 64 + lane;

        float q[32];
        const float* qrow = base + (size_t)s * 768 + h * 32;
        #pragma unroll
        for (int i = 0; i < 8; ++i) {
            float4 t4 = *(const float4*)&qrow[i * 4];
            q[i * 4 + 0] = t4.x * scale; q[i * 4 + 1] = t4.y * scale;
            q[i * 4 + 2] = t4.z * scale; q[i * 4 + 3] = t4.w * scale;
        }

        int qlen = 16 * (chunk + 1);          // per-wave share of [0, 64*(chunk+1))
        int t0 = wave * qlen, t1 = t0 + qlen;
        float m = -1e30f, l = 0.f, O[32] = {};
        for (int t = t0; t < t1; ++t) {
            const float* kr = base + (size_t)t * 768 + 256 + h * 32;
            float d0 = 0.f, d1 = 0.f, d2 = 0.f, d3 = 0.f;
            #pragma unroll
            for (int k = 0; k < 32; k += 4) {
                d0 += q[k + 0] * kr[k + 0];
                d1 += q[k + 1] * kr[k + 1];
                d2 += q[k + 2] * kr[k + 2];
                d3 += q[k + 3] * kr[k + 3];
            }
            float sc = (d0 + d1) + (d2 + d3);
            sc = (t <= s) ? sc : -1e30f;

            if (__any(sc > m + 8.f)) {        // deferred rescale
                float mn = fmaxf(m, sc);
                float corr = __expf(m - mn);
                l *= corr;
                #pragma unroll
                for (int k = 0; k < 32; ++k) O[k] *= corr;
                m = mn;
            }
            float p = __expf(sc - m);
            l += p;
            const float* vr = base + (size_t)t * 768 + 512 + h * 32;
            #pragma unroll
            for (int k = 0; k < 32; ++k) O[k] += p * vr[k];
        }

        Mls[wave][lane] = m; Lls[wave][lane] = l;
        #pragma unroll
        for (int k = 0; k < 32; ++k) Ols[wave][lane][k] = O[k];
        __syncthreads();

        // combine: thread -> (row = tid>>2, kq = tid&3); empty partials get w=0
        int row = threadIdx.x >> 2, kq = threadIdx.x & 3;
        float m0 = Mls[0][row], m1 = Mls[1][row], m2 = Mls[2][row], m3 = Mls[3][row];
        float Mx = fmaxf(fmaxf(m0, m1), fmaxf(m2, m3));
        float w0 = __expf(m0 - Mx), w1 = __expf(m1 - Mx), w2 = __expf(m2 - Mx), w3 = __expf(m3 - Mx);
        float L = w0 * Lls[0][row] + w1 * Lls[1][row] + w2 * Lls[2][row] + w3 * Lls[3][row];
        float inv = 1.f / L;
        uint4 outp;
        unsigned int* op = (unsigned int*)&outp;
        #pragma unroll
        for (int jj = 0; jj < 4; ++jj) {
            int k0i = kq * 8 + jj * 2;
            float o0 = (w0 * Ols[0][row][k0i] + w1 * Ols[1][row][k0i] +
                        w2 * Ols[2][row][k0i] + w3 * Ols[3][row][k0i]) * inv;
            float o1 = (w0 * Ols[0][row][k0i + 1] + w1 * Ols[1][row][k0i + 1] +
                        w2 * Ols[2][row][k0i + 1] + w3 * Ols[3][row][k0i + 1]) * inv;
            op[jj] = (unsigned int)f2bf(o0) | ((unsigned int)f2bf(o1) << 16);
        }
        *(uint4*)&ctx[(size_t)(b * S_ + chunk * 64 + row) * D_ + h * 32 + kq * 8] = outp;
        __syncthreads();   // LDS reused by next rep
    }
}

// ---------------------------------------------------------------------------
// out[t] = x[t] + LayerNorm(in[t]) * g + be ; BF16OUT: write bf16 (for GEMM A)
// ---------------------------------------------------------------------------
template <int BF16OUT>
__global__ __launch_bounds__(256) void ln_residual(const float* __restrict__ in,
                                                   const float* __restrict__ x,
                                                   const float* __restrict__ g,
                                                   const float* __restrict__ be,
                                                   void* __restrict__ out) {
    int token = blockIdx.x * 4 + (threadIdx.x >> 6);
    int lane = threadIdx.x & 63;
    const float* row = in + (size_t)token * D_;
    float4 v = *(const float4*)&row[lane * 4];
    float s  = v.x + v.y + v.z + v.w;
    float s2 = v.x * v.x + v.y * v.y + v.z * v.z + v.w * v.w;
    #pragma unroll
    for (int off = 1; off < 64; off <<= 1) {
        s  += __shfl_xor(s, off);
        s2 += __shfl_xor(s2, off);
    }
    float mu  = s * (1.f / D_);
    float var = s2 * (1.f / D_) - mu * mu;
    float r   = rsqrtf(var + 1e-5f);
    float4 xv = *(const float4*)&x[(size_t)token * D_ + lane * 4];
    float4 gv = *(const float4*)&g[lane * 4];
    float4 bv = *(const float4*)&be[lane * 4];
    float4 o;
    o.x = xv.x + (v.x - mu) * r * gv.x + bv.x;
    o.y = xv.y + (v.y - mu) * r * gv.y + bv.y;
    o.z = xv.z + (v.z - mu) * r * gv.z + bv.z;
    o.w = xv.w + (v.w - mu) * r * gv.w + bv.w;
    if (BF16OUT) {
        ushort4 o4; o4.x = f2bf(o.x); o4.y = f2bf(o.y); o4.z = f2bf(o.z); o4.w = f2bf(o.w);
        *(ushort4*)((unsigned short*)out + (size_t)token * D_ + lane * 4) = o4;
    } else {
        *(float4*)((float*)out + (size_t)token * D_ + lane * 4) = o;
    }
}

// ---------------------------------------------------------------------------
extern "C" void kernel_launch(void* const* d_in, const int* in_sizes, int n_in,
                              void* d_out, int out_size, void* d_ws, size_t ws_size,
                              hipStream_t stream) {
    (void)in_sizes; (void)n_in; (void)out_size; (void)ws_size;
    const float* x      = (const float*)d_in[0];
    const float* wq     = (const float*)d_in[1];
    const float* wk     = (const float*)d_in[2];
    const float* wv     = (const float*)d_in[3];
    const float* w_proj = (const float*)d_in[4];
    const float* w1     = (const float*)d_in[5];
    const float* b1     = (const float*)d_in[6];
    const float* w2     = (const float*)d_in[7];
    const float* b2     = (const float*)d_in[8];
    const float* g1     = (const float*)d_in[9];
    const float* be1    = (const float*)d_in[10];
    const float* g2     = (const float*)d_in[11];
    const float* be2    = (const float*)d_in[12];
    float* out = (float*)d_out;

    // workspace byte layout (peak 68.7 MB; regions reused when dead):
    char* W = (char*)d_ws;
    float*          qkv     = (float*)(W + 0);            // [0, 50331648) fp32 T x 768
    float*          attnout = (float*)(W + 0);            // over dead qkv   (16.7 MB)
    float*          ffout   = (float*)(W + 0);            // over dead attnout
    unsigned short* ff1     = (unsigned short*)(W + 16777216);  // [16.7M, 50.3M) bf16 T x 1024
    unsigned short* xb      = (unsigned short*)(W + 50331648);  // 8.39 MB
    unsigned short* Wqkv_t  = (unsigned short*)(W + 58720256);  // 768x256
    unsigned short* Wproj_t = (unsigned short*)(W + 59113472);  // 256x256
    unsigned short* W1_t    = (unsigned short*)(W + 59244544);  // 1024x256
    unsigned short* W2_t    = (unsigned short*)(W + 59768832);  // 256x1024
    unsigned short* ctx     = (unsigned short*)(W + 60293120);  // bf16 T x 256
    unsigned short* hbuf    = (unsigned short*)(W + 60293120);  // over dead ctx

    // input conversion + weight packing (tiny)
    f2b_kernel<<<(T_ * D_ / 4 + 255) / 256, 256, 0, stream>>>(x, xb, T_ * D_ / 4);
    pack_qkvw<<<768, 256, 0, stream>>>(wq, wk, wv, Wqkv_t);
    pack_t<<<256, 256, 0, stream>>>(w_proj, Wproj_t, 256, 256);
    pack_t<<<1024, 256, 0, stream>>>(w1, W1_t, 256, 1024);
    pack_t<<<1024, 256, 0, stream>>>(w2, W2_t, 1024, 256);

    // QKV projection: [16384,256] @ [256,768] -> fp32
    gemm_mfma<0><<<dim3(768 / 128, T_ / 128), 256, 0, stream>>>(xb, Wqkv_t, nullptr, qkv, T_, 768, 256);

    // causal attention -> ctx bf16
    attn_kernel<<<B_ * H_ * 4, 256, 0, stream>>>(qkv, ctx);

    // output projection: [16384,256] @ [256,256] -> fp32 (over dead qkv)
    gemm_mfma<0><<<dim3(256 / 128, T_ / 128), 256, 0, stream>>>(ctx, Wproj_t, nullptr, attnout, T_, 256, 256);

    // h = x + LN1(attnout) -> bf16
    ln_residual<1><<<T_ / 4, 256, 0, stream>>>(attnout, x, g1, be1, hbuf);

    // ff1 = relu(h @ w1 + b1) -> bf16
    gemm_mfma<7><<<dim3(FF_ / 128, T_ / 128), 256, 0, stream>>>(hbuf, W1_t, b1, ff1, T_, FF_, 256);

    // ffout = ff1 @ w2 + b2 -> fp32
    gemm_mfma<1><<<dim3(256 / 128, T_ / 128), 256, 0, stream>>>(ff1, W2_t, b2, ffout, T_, 256, 1024);

    // out = x + LN2(ffout)
    ln_residual<0><<<T_ / 4, 256, 0, stream>>>(ffout, x, g2, be2, out);
}

// Round 3
// 144.963 us; speedup vs baseline: 4.1140x; 2.8424x over previous
//
#include <hip/hip_runtime.h>
#include <hip/hip_bf16.h>

#define B_   32
#define S_   512
#define D_   256
#define H_   8
#define E_   32
#define FF_  1024
#define T_   (B_ * S_)   // 16384 tokens

typedef __attribute__((ext_vector_type(8))) short short8;
typedef __attribute__((ext_vector_type(4))) float f32x4;

// round-to-nearest-even fp32 -> bf16
static __device__ __forceinline__ unsigned short f2bf(float f) {
    union { float f; unsigned int u; } c; c.f = f;
    unsigned int u = c.u;
    u += 0x7fffu + ((u >> 16) & 1u);
    return (unsigned short)(u >> 16);
}

#define GLOAD16(g, l) __builtin_amdgcn_global_load_lds( \
    (const __attribute__((address_space(1))) void*)(g), \
    (__attribute__((address_space(3))) void*)(l), 16, 0, 0)

// ---------------------------------------------------------------------------
// fp32 -> bf16 elementwise
// ---------------------------------------------------------------------------
__global__ void f2b_kernel(const float* __restrict__ in, unsigned short* __restrict__ outp, int n4) {
    int i = blockIdx.x * 256 + threadIdx.x;
    if (i >= n4) return;
    float4 v = *(const float4*)&in[(size_t)i * 4];
    ushort4 o; o.x = f2bf(v.x); o.y = f2bf(v.y); o.z = f2bf(v.z); o.w = f2bf(v.w);
    *(ushort4*)&outp[(size_t)i * 4] = o;
}

// wq/wk/wv [H][D][E] -> Wt[768][256] bf16; wq gets softmax scale folded in.
__global__ void pack_qkvw(const float* __restrict__ wq, const float* __restrict__ wk,
                          const float* __restrict__ wv, unsigned short* __restrict__ Wt) {
    int idx = blockIdx.x * 256 + threadIdx.x;   // 768*256
    int nn = idx >> 8, k = idx & 255;
    int which = nn >> 8, r = nn & 255, h = r >> 5, e = r & 31;
    const float* w = (which == 0) ? wq : (which == 1 ? wk : wv);
    float v = w[(h * D_ + k) * E_ + e];
    if (which == 0) v *= 0.17677669529663687f;   // 1/sqrt(32), exact fold
    Wt[idx] = f2bf(v);
}

// w [K][N] fp32 -> Wt [N][K] bf16
__global__ void pack_t(const float* __restrict__ w, unsigned short* __restrict__ Wt, int K, int N) {
    int idx = blockIdx.x * 256 + threadIdx.x;
    if (idx >= N * K) return;
    int nn = idx / K, k = idx - nn * K;
    Wt[idx] = f2bf(w[(size_t)k * N + nn]);
}

// ---------------------------------------------------------------------------
// bf16 MFMA GEMM (unchanged from round 1, proven): C = A[M][K] @ Bt[N][K]^T
// EP bits: 1=bias, 2=relu, 4=bf16 output
// ---------------------------------------------------------------------------
template <int EP>
__global__ __launch_bounds__(256) void gemm_mfma(const unsigned short* __restrict__ A,
                                                 const unsigned short* __restrict__ Bt,
                                                 const float* __restrict__ bias,
                                                 void* __restrict__ Cout,
                                                 int M, int N, int K) {
    __shared__ char smem[32768];
    const int tid = threadIdx.x;
    const int bm = blockIdx.y * 128, bn = blockIdx.x * 128;
    const int wave = tid >> 6, lane = tid & 63;
    const int l15 = lane & 15, kc = lane >> 4;
    const int wr = (wave >> 1) * 64, wc = (wave & 1) * 64;

    auto stage = [&](int buf, int kt) {
        int k0 = kt * 32;
        char* aBase = smem + buf * 8192;
        char* bBase = smem + 16384 + buf * 8192;
        #pragma unroll
        for (int j = 0; j < 2; ++j) {
            int o = j * 256 + tid;
            int r = o >> 2, c = o & 3;
            int g = c ^ ((r >> 1) & 3);
            GLOAD16(A + (size_t)(bm + r) * K + k0 + g * 8, aBase + o * 16);
            GLOAD16(Bt + (size_t)(bn + r) * K + k0 + g * 8, bBase + o * 16);
        }
    };

    f32x4 acc[4][4];
    #pragma unroll
    for (int m = 0; m < 4; ++m)
        #pragma unroll
        for (int n = 0; n < 4; ++n) acc[m][n] = (f32x4){0.f, 0.f, 0.f, 0.f};

    const int NT = K >> 5;
    stage(0, 0);
    __syncthreads();

    int buf = 0;
    for (int kt = 0; kt < NT; ++kt) {
        if (kt + 1 < NT) stage(buf ^ 1, kt + 1);
        const char* aBase = smem + buf * 8192;
        const char* bBase = smem + 16384 + buf * 8192;
        short8 afr[4], bfr[4];
        #pragma unroll
        for (int m = 0; m < 4; ++m) {
            int row = wr + m * 16 + l15;
            int cc = kc ^ ((row >> 1) & 3);
            afr[m] = *(const short8*)(aBase + row * 64 + cc * 16);
        }
        #pragma unroll
        for (int n = 0; n < 4; ++n) {
            int row = wc + n * 16 + l15;
            int cc = kc ^ ((row >> 1) & 3);
            bfr[n] = *(const short8*)(bBase + row * 64 + cc * 16);
        }
        #pragma unroll
        for (int m = 0; m < 4; ++m)
            #pragma unroll
            for (int n = 0; n < 4; ++n)
                acc[m][n] = __builtin_amdgcn_mfma_f32_16x16x32_bf16(afr[m], bfr[n], acc[m][n], 0, 0, 0);
        __syncthreads();
        buf ^= 1;
    }

    #pragma unroll
    for (int n = 0; n < 4; ++n) {
        int col = bn + wc + n * 16 + l15;
        float bv = (EP & 1) ? bias[col] : 0.f;
        #pragma unroll
        for (int m = 0; m < 4; ++m) {
            int row0 = bm + wr + m * 16 + kc * 4;
            #pragma unroll
            for (int j = 0; j < 4; ++j) {
                float v = acc[m][n][j] + bv;
                if (EP & 2) v = fmaxf(v, 0.f);
                if (EP & 4) ((unsigned short*)Cout)[(size_t)(row0 + j) * N + col] = f2bf(v);
                else        ((float*)Cout)[(size_t)(row0 + j) * N + col] = v;
            }
        }
    }
}

// ---------------------------------------------------------------------------
// V transpose: qkv bf16 [T][768] V-part -> Vt [bh][32][512] bf16
// One block per (b,h); LDS tile, coalesced both sides.
// ---------------------------------------------------------------------------
__global__ __launch_bounds__(256) void transpose_v(const unsigned short* __restrict__ qkvb,
                                                   unsigned short* __restrict__ vtg) {
    __shared__ unsigned short tile[512][34];   // pad 34 -> ~conflict-free col reads
    int bh = blockIdx.x;
    int b = bh >> 3, h = bh & 7;
    int tid = threadIdx.x;
    #pragma unroll
    for (int it = 0; it < 8; ++it) {
        int slot = it * 256 + tid;
        int s = slot >> 2, e0 = (slot & 3) << 3;
        short8 v = *(const short8*)(qkvb + (size_t)(b * 512 + s) * 768 + 512 + h * 32 + e0);
        const unsigned int* u = (const unsigned int*)&v;
        #pragma unroll
        for (int p = 0; p < 4; ++p)
            *(unsigned int*)&tile[s][e0 + p * 2] = u[p];
    }
    __syncthreads();
    int e = tid >> 3, i8 = tid & 7;
    #pragma unroll
    for (int it2 = 0; it2 < 8; ++it2) {
        int s0 = it2 * 64 + i8 * 8;
        ushort4 w0, w1;
        w0.x = tile[s0 + 0][e]; w0.y = tile[s0 + 1][e];
        w0.z = tile[s0 + 2][e]; w0.w = tile[s0 + 3][e];
        w1.x = tile[s0 + 4][e]; w1.y = tile[s0 + 5][e];
        w1.z = tile[s0 + 6][e]; w1.w = tile[s0 + 7][e];
        unsigned short* dst = vtg + (size_t)bh * 16384 + e * 512 + s0;
        *(ushort4*)dst = w0;
        *(ushort4*)(dst + 4) = w1;
    }
}

// ---------------------------------------------------------------------------
// MFMA flash attention. Grid = B*H*2; block = 4 waves; wave owns 64 q-rows
// (q0 = qh*256 + wave*64). S^T = mfma(K,Q): lane holds St[t=kc*4+j][q=l15]
// -> per-q reduction = in-lane + shfl_xor(16,32). P through per-wave
// swizzled LDS [64][64] bf16; V staged in LDS as [32][512] (chunk-XOR swz).
// ---------------------------------------------------------------------------
__global__ __launch_bounds__(256, 2) void attn_mfma(const unsigned short* __restrict__ qkvb,
                                                    const unsigned short* __restrict__ vtg,
                                                    unsigned short* __restrict__ ctx) {
    __shared__ unsigned short vlds[32 * 512];      // 32 KB
    __shared__ unsigned short plds[4][64 * 64];    // 32 KB
    const int blk = blockIdx.x;
    const int bh = blk >> 1, qh = blk & 1;
    const int b = bh >> 3, h = bh & 7;
    const int tid = threadIdx.x;
    const int wave = tid >> 6, lane = tid & 63;
    const int l15 = lane & 15, kc = lane >> 4;
    const int q0 = qh * 256 + wave * 64;

    // stage Vt (full 512 t) with inverse-swizzled source, linear LDS dest
    #pragma unroll
    for (int it = 0; it < 8; ++it) {
        int slot = it * 256 + tid;
        int e = slot >> 6, c = slot & 63;
        int g = c ^ (e & 7);
        GLOAD16(vtg + (size_t)bh * 16384 + e * 512 + g * 8, (char*)vlds + slot * 16);
    }

    // Q fragments (softmax scale folded into wq at pack time)
    short8 qf[4];
    #pragma unroll
    for (int qm = 0; qm < 4; ++qm)
        qf[qm] = *(const short8*)(qkvb + (size_t)(b * 512 + q0 + qm * 16 + l15) * 768 + h * 32 + kc * 8);

    __syncthreads();

    f32x4 Ofr[4][2];
    float mreg[4], lreg[4];
    #pragma unroll
    for (int qm = 0; qm < 4; ++qm) {
        Ofr[qm][0] = (f32x4){0.f, 0.f, 0.f, 0.f};
        Ofr[qm][1] = (f32x4){0.f, 0.f, 0.f, 0.f};
        mreg[qm] = -1e30f; lreg[qm] = 0.f;
    }
    unsigned short* pw = plds[wave];
    const int xsw = (l15 & 7) << 1;   // P chunk swizzle (even -> preserves b128 pairing)

    const int nt = (q0 + 64) >> 6;
    for (int ti = 0; ti < nt; ++ti) {
        const int t0 = ti * 64;
        // K fragments straight from qkv bf16 (L2-resident; 64B/row segments)
        short8 kf[4];
        #pragma unroll
        for (int tn = 0; tn < 4; ++tn)
            kf[tn] = *(const short8*)(qkvb + (size_t)(b * 512 + t0 + tn * 16 + l15) * 768 + 256 + h * 32 + kc * 8);
        const bool diag = (ti == nt - 1);

        #pragma unroll
        for (int qm = 0; qm < 4; ++qm) {
            f32x4 st[4];
            #pragma unroll
            for (int tn = 0; tn < 4; ++tn)
                st[tn] = __builtin_amdgcn_mfma_f32_16x16x32_bf16(kf[tn], qf[qm],
                                                                 (f32x4){0.f, 0.f, 0.f, 0.f}, 0, 0, 0);
            if (diag) {
                int q_rel = qm * 16 + l15;
                #pragma unroll
                for (int tn = 0; tn < 4; ++tn)
                    #pragma unroll
                    for (int j = 0; j < 4; ++j)
                        if (tn * 16 + kc * 4 + j > q_rel) st[tn][j] = -1e30f;
            }
            // per-q (l15) tile max: in-lane over 16, then across kc groups
            float tmax = st[0][0];
            #pragma unroll
            for (int tn = 0; tn < 4; ++tn)
                #pragma unroll
                for (int j = 0; j < 4; ++j) tmax = fmaxf(tmax, st[tn][j]);
            tmax = fmaxf(tmax, __shfl_xor(tmax, 16));
            tmax = fmaxf(tmax, __shfl_xor(tmax, 32));

            if (__any(tmax > mreg[qm] + 8.f)) {      // deferred rescale (T13)
                float mn = fmaxf(mreg[qm], tmax);
                float corr = __expf(mreg[qm] - mn);
                lreg[qm] *= corr;
                #pragma unroll
                for (int j = 0; j < 4; ++j) {
                    float cj = __shfl(corr, kc * 4 + j, 16);  // row-space broadcast
                    Ofr[qm][0][j] *= cj;
                    Ofr[qm][1][j] *= cj;
                }
                mreg[qm] = mn;
            }

            float psum = 0.f;
            #pragma unroll
            for (int tn = 0; tn < 4; ++tn) {
                float p0 = __expf(st[tn][0] - mreg[qm]);
                float p1 = __expf(st[tn][1] - mreg[qm]);
                float p2 = __expf(st[tn][2] - mreg[qm]);
                float p3 = __expf(st[tn][3] - mreg[qm]);
                psum += (p0 + p1) + (p2 + p3);
                uint2 w;
                w.x = (unsigned)f2bf(p0) | ((unsigned)f2bf(p1) << 16);
                w.y = (unsigned)f2bf(p2) | ((unsigned)f2bf(p3) << 16);
                int tc = (tn * 4 + kc) ^ xsw;        // swizzled 8B chunk
                *(uint2*)(pw + (qm * 16 + l15) * 64 + tc * 4) = w;
            }
            psum += __shfl_xor(psum, 16);
            psum += __shfl_xor(psum, 32);
            lreg[qm] += psum;
        }

        // PV: O[q][e] += P[q][t] * V[t][e]
        #pragma unroll
        for (int tt = 0; tt < 2; ++tt) {
            short8 pa[4];
            #pragma unroll
            for (int qm = 0; qm < 4; ++qm) {
                int tcr = (tt * 8 + kc * 2) ^ xsw;
                pa[qm] = *(const short8*)(pw + (qm * 16 + l15) * 64 + tcr * 4);
            }
            short8 vt[2];
            #pragma unroll
            for (int n = 0; n < 2; ++n) {
                int e = n * 16 + l15;
                int c = ((t0 >> 3) + tt * 4 + kc) ^ (e & 7);
                vt[n] = *(const short8*)(vlds + e * 512 + c * 8);
            }
            #pragma unroll
            for (int qm = 0; qm < 4; ++qm)
                #pragma unroll
                for (int n = 0; n < 2; ++n)
                    Ofr[qm][n] = __builtin_amdgcn_mfma_f32_16x16x32_bf16(pa[qm], vt[n], Ofr[qm][n], 0, 0, 0);
        }
    }

    // epilogue: O row q = q0+qm*16+kc*4+j, col e = n*16+l15
    #pragma unroll
    for (int qm = 0; qm < 4; ++qm) {
        float linv = 1.f / lreg[qm];
        #pragma unroll
        for (int j = 0; j < 4; ++j) {
            float lj = __shfl(linv, kc * 4 + j, 16);
            size_t base = (size_t)(b * 512 + q0 + qm * 16 + kc * 4 + j) * 256 + h * 32;
            ctx[base + l15]      = f2bf(Ofr[qm][0][j] * lj);
            ctx[base + 16 + l15] = f2bf(Ofr[qm][1][j] * lj);
        }
    }
}

// ---------------------------------------------------------------------------
// out[t] = x[t] + LayerNorm(in[t]) * g + be
// ---------------------------------------------------------------------------
template <int BF16OUT>
__global__ __launch_bounds__(256) void ln_residual(const float* __restrict__ in,
                                                   const float* __restrict__ x,
                                                   const float* __restrict__ g,
                                                   const float* __restrict__ be,
                                                   void* __restrict__ out) {
    int token = blockIdx.x * 4 + (threadIdx.x >> 6);
    int lane = threadIdx.x & 63;
    const float* row = in + (size_t)token * D_;
    float4 v = *(const float4*)&row[lane * 4];
    float s  = v.x + v.y + v.z + v.w;
    float s2 = v.x * v.x + v.y * v.y + v.z * v.z + v.w * v.w;
    #pragma unroll
    for (int off = 1; off < 64; off <<= 1) {
        s  += __shfl_xor(s, off);
        s2 += __shfl_xor(s2, off);
    }
    float mu  = s * (1.f / D_);
    float var = s2 * (1.f / D_) - mu * mu;
    float r   = rsqrtf(var + 1e-5f);
    float4 xv = *(const float4*)&x[(size_t)token * D_ + lane * 4];
    float4 gv = *(const float4*)&g[lane * 4];
    float4 bv = *(const float4*)&be[lane * 4];
    float4 o;
    o.x = xv.x + (v.x - mu) * r * gv.x + bv.x;
    o.y = xv.y + (v.y - mu) * r * gv.y + bv.y;
    o.z = xv.z + (v.z - mu) * r * gv.z + bv.z;
    o.w = xv.w + (v.w - mu) * r * gv.w + bv.w;
    if (BF16OUT) {
        ushort4 o4; o4.x = f2bf(o.x); o4.y = f2bf(o.y); o4.z = f2bf(o.z); o4.w = f2bf(o.w);
        *(ushort4*)((unsigned short*)out + (size_t)token * D_ + lane * 4) = o4;
    } else {
        *(float4*)((float*)out + (size_t)token * D_ + lane * 4) = o;
    }
}

// ---------------------------------------------------------------------------
extern "C" void kernel_launch(void* const* d_in, const int* in_sizes, int n_in,
                              void* d_out, int out_size, void* d_ws, size_t ws_size,
                              hipStream_t stream) {
    (void)in_sizes; (void)n_in; (void)out_size; (void)ws_size;
    const float* x      = (const float*)d_in[0];
    const float* wq     = (const float*)d_in[1];
    const float* wk     = (const float*)d_in[2];
    const float* wv     = (const float*)d_in[3];
    const float* w_proj = (const float*)d_in[4];
    const float* w1     = (const float*)d_in[5];
    const float* b1     = (const float*)d_in[6];
    const float* w2     = (const float*)d_in[7];
    const float* b2     = (const float*)d_in[8];
    const float* g1     = (const float*)d_in[9];
    const float* be1    = (const float*)d_in[10];
    const float* g2     = (const float*)d_in[11];
    const float* be2    = (const float*)d_in[12];
    float* out = (float*)d_out;

    // workspace layout (bytes), peak 68.68 MB (same as round-1 proven max):
    char* W = (char*)d_ws;
    unsigned short* qkvb    = (unsigned short*)(W + 0);         // bf16 T x 768, [0, 25.17M)
    unsigned short* vtg     = (unsigned short*)(W + 25165824);  // bf16 256 x 32 x 512
    unsigned short* ctx     = (unsigned short*)(W + 33554432);  // bf16 T x 256
    unsigned short* xb      = (unsigned short*)(W + 41943040);  // bf16 T x 256
    float*          attnout = (float*)(W + 0);                  // over dead qkvb
    unsigned short* hbuf    = (unsigned short*)(W + 16777216);  // over dead qkvb tail
    unsigned short* ff1     = (unsigned short*)(W + 33554432);  // over dead ctx (33.55M)
    float*          ffout   = (float*)(W + 0);                  // over dead attnout
    unsigned short* Wqkv_t  = (unsigned short*)(W + 67108864);
    unsigned short* Wproj_t = (unsigned short*)(W + 67502080);
    unsigned short* W1_t    = (unsigned short*)(W + 67633152);
    unsigned short* W2_t    = (unsigned short*)(W + 68157440);

    f2b_kernel<<<(T_ * D_ / 4 + 255) / 256, 256, 0, stream>>>(x, xb, T_ * D_ / 4);
    pack_qkvw<<<768, 256, 0, stream>>>(wq, wk, wv, Wqkv_t);
    pack_t<<<256, 256, 0, stream>>>(w_proj, Wproj_t, 256, 256);
    pack_t<<<1024, 256, 0, stream>>>(w1, W1_t, 256, 1024);
    pack_t<<<1024, 256, 0, stream>>>(w2, W2_t, 1024, 256);

    // QKV projection -> bf16 qkv  [16384,256] @ [256,768]
    gemm_mfma<4><<<dim3(768 / 128, T_ / 128), 256, 0, stream>>>(xb, Wqkv_t, nullptr, qkvb, T_, 768, 256);

    // V transpose -> [bh][32][512] bf16
    transpose_v<<<B_ * H_, 256, 0, stream>>>(qkvb, vtg);

    // MFMA flash attention -> ctx bf16
    attn_mfma<<<B_ * H_ * 2, 256, 0, stream>>>(qkvb, vtg, ctx);

    // output projection: [16384,256] @ [256,256] -> fp32 (over dead qkvb)
    gemm_mfma<0><<<dim3(256 / 128, T_ / 128), 256, 0, stream>>>(ctx, Wproj_t, nullptr, attnout, T_, 256, 256);

    // h = x + LN1(attnout) -> bf16
    ln_residual<1><<<T_ / 4, 256, 0, stream>>>(attnout, x, g1, be1, hbuf);

    // ff1 = relu(h @ w1 + b1) -> bf16
    gemm_mfma<7><<<dim3(FF_ / 128, T_ / 128), 256, 0, stream>>>(hbuf, W1_t, b1, ff1, T_, FF_, 256);

    // ffout = ff1 @ w2 + b2 -> fp32
    gemm_mfma<1><<<dim3(256 / 128, T_ / 128), 256, 0, stream>>>(ff1, W2_t, b2, ffout, T_, 256, 1024);

    // out = x + LN2(ffout)
    ln_residual<0><<<T_ / 4, 256, 0, stream>>>(ffout, x, g2, be2, out);
}